// Round 2
// baseline (515.011 us; speedup 1.0000x reference)
//
#include <hip/hip_runtime.h>
#include <math.h>

// Problem constants: B=512, N=600, H=256, K=9, WIN=129
#define BB   512
#define NN   600
#define HH   256
#define KS   9
#define WIN  129
#define PADW 4
#define PWIN 137           // WIN + 2*PAD
#define NP   608           // N + 2*PAD

// One block per batch, 512 threads (8 waves).
// __launch_bounds__(512, 8): min 8 waves/SIMD -> VGPR cap 64 -> 4 blocks/CU
// -> 32 waves/CU (max) and all 512 blocks co-resident. Inter-block overlap
// hides the per-block serial chain (the prior 1024-thread/16-wave version
// was ~1 block/CU and latency-bound at ~18% of HBM BW).
// LDS ~16 KB (conv_w staging dropped; it is block-invariant -> L2-resident).
__global__ __launch_bounds__(512, 8) void attn_kernel(
    const float* __restrict__ tokens,       // (B,N,H)
    const float* __restrict__ token_keys,   // (B,H,N)
    const int*   __restrict__ num_tokens,   // (B,)
    const float* __restrict__ query,        // (B,H)
    const float* __restrict__ alignment,    // (B,NP)
    const float* __restrict__ cum_align,    // (B,NP)
    const int*   __restrict__ window_start, // (B,)
    const float* __restrict__ conv_w,       // (H,2,K)
    const float* __restrict__ conv_b,       // (H,)
    float* __restrict__ out)
{
  const int b    = blockIdx.x;
  const int t    = threadIdx.x;
  const int lane = t & 63;
  const int wv   = t >> 6;            // 0..7

  __shared__ float sq[HH];            // query row (1 KB)
  __shared__ float p0[PWIN], p1[PWIN];
  __shared__ float cred[19][8];       // conv-fold partials
  __shared__ float w128red[4];        // w=128 column dot partials
  __shared__ float sqc[19];           // folded conv scalars
  __shared__ float sS[8][130];        // per-h-group score partials
  __shared__ float salign[WIN];       // raw scores, then e-values
  __shared__ __align__(16) float sctx[8][HH];  // context partials (8 KB)
  __shared__ float s_sum;
  __shared__ int   s_arg;

  const int ws = window_start[b];
  const int nt = num_tokens[b];
  const float* __restrict__ Kb = token_keys + (size_t)b * (HH * NN);

  // Prefetch cum_align rows needed by the out3 epilogue (2 regs, hides latency)
  const float cum0 = cum_align[b * NP + t];                        // t < 512 < NP
  const float cum1 = (t + 512 < NP) ? cum_align[b * NP + t + 512] : 0.f;

  // ---- Stage small inputs to LDS ----
  float qreg = 0.f;
  if (t < HH) { qreg = query[b * HH + t]; sq[t] = qreg; }
  if (t < PWIN) {
    p0[t] = cum_align[b * NP + ws + t] * (1.0f / 1.5f) - 1.0f;
    p1[t] = alignment[b * NP + ws + t] * 2.0f - 1.0f;
  }
  __syncthreads();

  // ---- Phase B: keys dot. wave wv owns h-rows [wv*32, wv*32+32), cols lane & lane+64 ----
  {
    const float* __restrict__ Kp  = Kb + (size_t)(wv * 32) * NN + ws;
    const float* __restrict__ sqp = sq + wv * 32;
    float a0 = 0.f, a1 = 0.f;
    #pragma unroll 4
    for (int h = 0; h < 32; ++h) {
      const float q = sqp[h];
      a0 += q * Kp[(size_t)h * NN + lane];
      a1 += q * Kp[(size_t)h * NN + 64 + lane];
    }
    sS[wv][lane]      = a0;
    sS[wv][64 + lane] = a1;
  }

  // ---- w=128 column dot (threads 0..255, thread t owns h=t) ----
  if (t < HH) {
    float v = qreg * Kb[(size_t)t * NN + ws + 128];
    #pragma unroll
    for (int off = 32; off; off >>= 1) v += __shfl_xor(v, off, 64);
    if (lane == 0) w128red[wv] = v;
  }

  // ---- Conv fold (reads conv_w/conv_b straight from global: L2-resident) ----
  if (t < 152) {
    const int j = t >> 3, seg = t & 7;
    const int h0 = seg * 32;
    float a = 0.f;
    if (j < 18) {
      #pragma unroll 4
      for (int h = 0; h < 32; ++h) a += sq[h0 + h] * conv_w[(h0 + h) * 18 + j];
    } else {
      #pragma unroll 4
      for (int h = 0; h < 32; ++h) a += sq[h0 + h] * conv_b[h0 + h];
    }
    cred[j][seg] = a;
  }
  __syncthreads();

  if (t < 19) {
    const float* c = cred[t];
    sqc[t] = ((c[0] + c[1]) + (c[2] + c[3])) + ((c[4] + c[5]) + (c[6] + c[7]));
  }
  __syncthreads();

  // ---- Score assembly (threads 0..128) -> raw scores in salign ----
  if (t < WIN) {
    float dot;
    if (t < 128) {
      dot = 0.f;
      #pragma unroll
      for (int g = 0; g < 8; ++g) dot += sS[g][t];
    } else {
      dot = w128red[0] + w128red[1] + w128red[2] + w128red[3];
    }
    float f = sqc[18];
    #pragma unroll
    for (int k = 0; k < KS; ++k) f += sqc[k] * p0[t + k] + sqc[9 + k] * p1[t + k];
    float sc = (dot + f) * 0.0625f;               // / sqrt(256)
    if (ws + t >= nt) sc = -INFINITY;
    salign[t] = sc;
  }
  __syncthreads();

  // ---- Fused softmax: max + argmax + exp + sum entirely inside wave 0 ----
  if (t < 64) {
    const float a0 = salign[t];
    const float a1 = salign[t + 64];
    const float a2 = (t == 0) ? salign[128] : -INFINITY;
    float m = a0; int idx = t;                    // first-index tie semantics
    if (a1 > m) { m = a1; idx = t + 64; }
    if (a2 > m) { m = a2; idx = 128; }
    #pragma unroll
    for (int off = 32; off; off >>= 1) {
      const float om = __shfl_xor(m, off, 64);
      const int   oi = __shfl_xor(idx, off, 64);
      if (om > m || (om == m && oi < idx)) { m = om; idx = oi; }
    }
    const float e0 = expf(a0 - m);
    const float e1 = expf(a1 - m);
    salign[t]      = e0;
    salign[t + 64] = e1;
    float s = e0 + e1;
    if (t == 0) { const float e2 = expf(a2 - m); salign[128] = e2; s += e2; }
    #pragma unroll
    for (int off = 32; off; off >>= 1) s += __shfl_xor(s, off, 64);
    if (t == 0) { s_sum = s; s_arg = idx; }
  }
  __syncthreads();

  const float inv = 1.0f / s_sum;                 // normalization folded into writes

  // ---- Output pointers ----
  float* out0 = out;                       // context     (B,H)
  float* out1 = out0 + BB * HH;            // unpadded    (B,N)
  float* out2 = out1 + BB * NN;            // full_align  (B,NP)
  float* out3 = out2 + BB * NP;            // cum+align   (B,NP)
  float* out4 = out3 + BB * NP;            // new_start   (B,) as float

  // ---- Phase C: context via float4. wave wv covers w = wv, wv+8, ... ----
  {
    const float* __restrict__ Tb = tokens + (size_t)b * (NN * HH) + (size_t)ws * HH;
    float4 acc = make_float4(0.f, 0.f, 0.f, 0.f);
    #pragma unroll 4
    for (int i = 0; i < 16; ++i) {
      const int w = wv + 8 * i;             // 0..127 across waves
      const float a = salign[w];
      const float4 v4 = ((const float4*)(Tb + (size_t)w * HH))[lane];
      acc.x += a * v4.x; acc.y += a * v4.y; acc.z += a * v4.z; acc.w += a * v4.w;
    }
    if (wv == 0) {                          // tail w = 128
      const float a = salign[128];
      const float4 v4 = ((const float4*)(Tb + (size_t)128 * HH))[lane];
      acc.x += a * v4.x; acc.y += a * v4.y; acc.z += a * v4.z; acc.w += a * v4.w;
    }
    ((float4*)&sctx[wv][0])[lane] = acc;
  }

  // ---- Scatter outputs (independent of sctx; overlaps other waves' Phase C) ----
  for (int j = t; j < NN; j += 512) {
    const float v = (j >= ws && j <= ws + 128) ? salign[j - ws] * inv : 0.f;
    out1[b * NN + j] = v;
  }
  {
    int j = t;
    const float v0 = (j >= ws + PADW && j <= ws + PADW + 128) ? salign[j - ws - PADW] * inv : 0.f;
    out2[b * NP + j] = v0;
    out3[b * NP + j] = v0 + cum0;
    j = t + 512;
    if (j < NP) {
      const float v1 = (j >= ws + PADW && j <= ws + PADW + 128) ? salign[j - ws - PADW] * inv : 0.f;
      out2[b * NP + j] = v1;
      out3[b * NP + j] = v1 + cum1;
    }
  }
  if (t == 0) {
    int jstar = ws + PADW + s_arg;
    int ns = jstar - (PWIN / 2);
    ns = max(ws, ns);
    ns = min(ns, nt - WIN);
    ns = max(ns, 0);
    out4[b] = (float)ns;
  }
  __syncthreads();

  // ---- Context final reduce + write ----
  if (t < HH) {
    float c = 0.f;
    #pragma unroll
    for (int v = 0; v < 8; ++v) c += sctx[v][t];
    out0[b * HH + t] = c * inv;
  }
}

extern "C" void kernel_launch(void* const* d_in, const int* in_sizes, int n_in,
                              void* d_out, int out_size, void* d_ws, size_t ws_size,
                              hipStream_t stream) {
  const float* tokens       = (const float*)d_in[0];
  // d_in[1] = tokens_mask (bool) — recomputed from num_tokens, unused
  const float* token_keys   = (const float*)d_in[2];
  const int*   num_tokens   = (const int*)d_in[3];
  const float* query        = (const float*)d_in[4];
  const float* alignment    = (const float*)d_in[5];
  const float* cum_align    = (const float*)d_in[6];
  const int*   window_start = (const int*)d_in[7];
  const float* conv_w       = (const float*)d_in[8];
  const float* conv_b       = (const float*)d_in[9];

  attn_kernel<<<BB, 512, 0, stream>>>(tokens, token_keys, num_tokens, query,
                                      alignment, cum_align, window_start,
                                      conv_w, conv_b, (float*)d_out);
}